// Round 1
// baseline (390.423 us; speedup 1.0000x reference)
//
#include <hip/hip_runtime.h>

typedef short short8 __attribute__((ext_vector_type(8)));
typedef float f32x4 __attribute__((ext_vector_type(4)));

#define N_NODES 100000
#define N_EDGES 1600000
#define D_IN 256
#define D_OUT 128

// ws layout (bytes)
#define OFF_H     0UL          // bf16 h: 100000*128*2 = 25,600,000
#define OFF_WP    25600000UL   // packed W bf16 fragments: 65,536
#define OFF_OFFS  25665536UL   // int[100001] row offsets (+pad) = 400,016
#define OFF_CNT   26065552UL   // int[100000] counts = 400,000
#define OFF_CNT2  26465552UL   // int[100000] cursors = 400,000
#define OFF_BS    26865552UL   // int[1024] block sums = 4,096
#define OFF_PCOL  26869648UL   // int[1.6M] = 6,400,000
#define OFF_PVAL  33269648UL   // float[1.6M] = 6,400,000

__device__ __forceinline__ unsigned short f2bf(float f) {
    unsigned int u = __builtin_bit_cast(unsigned int, f);
    u += 0x7fffu + ((u >> 16) & 1u);   // RNE
    return (unsigned short)(u >> 16);
}

// Pack W [256][128] fp32 -> bf16 MFMA B-fragments.
// Fragment order: idx t = ks*512 + nt*64 + lane, elems e=0..7 at k=ks*32+(lane>>4)*8+e, n=nt*16+(lane&15)
__global__ void wpack_k(const float* __restrict__ W, unsigned short* __restrict__ wp) {
    int t = blockIdx.x * 256 + threadIdx.x;
    if (t >= 4096) return;
    int ks = t >> 9, nt = (t >> 6) & 7, lane = t & 63;
    int g = lane >> 4, n = nt * 16 + (lane & 15);
    int k0 = ks * 32 + g * 8;
#pragma unroll
    for (int e = 0; e < 8; ++e)
        wp[t * 8 + e] = f2bf(W[(size_t)(k0 + e) * D_OUT + n]);
}

// h = bf16( x @ W + b ), one 16-row tile per wave, full N=128 in registers.
__global__ __launch_bounds__(256) void gemm_k(const float* __restrict__ x,
                                              const short8* __restrict__ wq,
                                              const float* __restrict__ b,
                                              unsigned short* __restrict__ h) {
    int wave = threadIdx.x >> 6, lane = threadIdx.x & 63;
    int tile = blockIdx.x * 4 + wave;
    if (tile * 16 >= N_NODES) return;
    int row0 = tile * 16;
    int r = lane & 15, g = lane >> 4;

    f32x4 acc[8];
#pragma unroll
    for (int nt = 0; nt < 8; ++nt)
#pragma unroll
        for (int j = 0; j < 4; ++j) acc[nt][j] = 0.f;

    float bv[8];
#pragma unroll
    for (int nt = 0; nt < 8; ++nt) bv[nt] = b[nt * 16 + r];

    const float* xp = x + (size_t)(row0 + r) * D_IN;
#pragma unroll
    for (int ks = 0; ks < 8; ++ks) {
        int k = ks * 32 + g * 8;
        short8 af;
#pragma unroll
        for (int e = 0; e < 8; ++e) af[e] = (short)f2bf(xp[k + e]);
#pragma unroll
        for (int nt = 0; nt < 8; ++nt) {
            short8 bf = wq[(ks * 8 + nt) * 64 + lane];
            acc[nt] = __builtin_amdgcn_mfma_f32_16x16x32_bf16(af, bf, acc[nt], 0, 0, 0);
        }
    }
#pragma unroll
    for (int nt = 0; nt < 8; ++nt)
#pragma unroll
        for (int j = 0; j < 4; ++j) {
            float v = acc[nt][j] + bv[nt];
            h[(size_t)(row0 + g * 4 + j) * D_OUT + nt * 16 + r] = f2bf(v);
        }
}

__global__ void count_k(const int* __restrict__ er, int* __restrict__ cnt) {
    int e = blockIdx.x * 256 + threadIdx.x;
    if (e < N_EDGES) atomicAdd(&cnt[er[e]], 1);
}

// Hillis-Steele inclusive scan per 1024-block; block sums out.
__global__ __launch_bounds__(1024) void scan1_k(const int* __restrict__ cnt, int* __restrict__ offs,
                                                int* __restrict__ bs, int n) {
    __shared__ int s[1024];
    int t = threadIdx.x;
    int i = blockIdx.x * 1024 + t;
    int v = (i < n) ? cnt[i] : 0;
    s[t] = v;
    __syncthreads();
    for (int off = 1; off < 1024; off <<= 1) {
        int tmp = (t >= off) ? s[t - off] : 0;
        __syncthreads();
        s[t] += tmp;
        __syncthreads();
    }
    if (i < n) offs[i] = s[t];
    if (t == 1023) bs[blockIdx.x] = s[1023];
}

__global__ void scan2_k(int* __restrict__ bs, int nb) {
    if (blockIdx.x == 0 && threadIdx.x == 0) {
        int run = 0;
        for (int bb = 0; bb < nb; ++bb) { int t = bs[bb]; bs[bb] = run; run += t; }
        bs[nb] = run;
    }
}

__global__ void scan3_k(int* __restrict__ offs, const int* __restrict__ cnt,
                        const int* __restrict__ bs, int n, int nb) {
    int i = blockIdx.x * 256 + threadIdx.x;
    if (i < n) offs[i] = offs[i] - cnt[i] + bs[i >> 10];
    if (i == 0) offs[n] = bs[nb];
}

__global__ void scatter_k(const int* __restrict__ er, const int* __restrict__ ec,
                          const float* __restrict__ ev, const int* __restrict__ offs,
                          int* __restrict__ cnt2, int* __restrict__ pcol, float* __restrict__ pval) {
    int e = blockIdx.x * 256 + threadIdx.x;
    if (e >= N_EDGES) return;
    int rrow = er[e];
    int pos = offs[rrow] + atomicAdd(&cnt2[rrow], 1);
    pcol[pos] = ec[e];
    pval[pos] = ev[e];
}

// One wave per output row: out[i,:] = relu( sum_e val*h[col] ), 2 cols per lane.
__global__ __launch_bounds__(256) void row_k(const unsigned int* __restrict__ h32,
                                             const int* __restrict__ offs,
                                             const int* __restrict__ pcol,
                                             const float* __restrict__ pval,
                                             float* __restrict__ out) {
    int gw = (blockIdx.x * 256 + threadIdx.x) >> 6;
    int lane = threadIdx.x & 63;
    if (gw >= N_NODES) return;
    int s = offs[gw], e2 = offs[gw + 1];
    float a0 = 0.f, a1 = 0.f;
    for (int e = s; e < e2; ++e) {
        int c = pcol[e];
        float v = pval[e];
        unsigned int hv = h32[(size_t)c * 64 + lane];
        float lo = __builtin_bit_cast(float, hv << 16);
        float hi = __builtin_bit_cast(float, hv & 0xffff0000u);
        a0 += v * lo;
        a1 += v * hi;
    }
    float2 o;
    o.x = a0 > 0.f ? a0 : 0.f;
    o.y = a1 > 0.f ? a1 : 0.f;
    reinterpret_cast<float2*>(out)[(size_t)gw * 64 + lane] = o;
}

extern "C" void kernel_launch(void* const* d_in, const int* in_sizes, int n_in,
                              void* d_out, int out_size, void* d_ws, size_t ws_size,
                              hipStream_t stream) {
    const float* x = (const float*)d_in[0];
    const float* W = (const float*)d_in[1];
    const float* b = (const float*)d_in[2];
    const int* er = (const int*)d_in[3];
    const int* ec = (const int*)d_in[4];
    const float* ev = (const float*)d_in[5];
    float* out = (float*)d_out;
    char* ws = (char*)d_ws;

    unsigned short* h = (unsigned short*)(ws + OFF_H);
    unsigned short* wp = (unsigned short*)(ws + OFF_WP);
    int* offs = (int*)(ws + OFF_OFFS);
    int* cnt = (int*)(ws + OFF_CNT);
    int* cnt2 = (int*)(ws + OFF_CNT2);
    int* bs = (int*)(ws + OFF_BS);
    int* pcol = (int*)(ws + OFF_PCOL);
    float* pval = (float*)(ws + OFF_PVAL);

    hipMemsetAsync(ws + OFF_CNT, 0, 800000, stream);  // cnt + cnt2

    wpack_k<<<16, 256, 0, stream>>>(W, wp);
    gemm_k<<<1563, 256, 0, stream>>>(x, (const short8*)wp, b, h);
    count_k<<<(N_EDGES + 255) / 256, 256, 0, stream>>>(er, cnt);
    scan1_k<<<98, 1024, 0, stream>>>(cnt, offs, bs, N_NODES);
    scan2_k<<<1, 64, 0, stream>>>(bs, 98);
    scan3_k<<<(N_NODES + 255) / 256, 256, 0, stream>>>(offs, cnt, bs, N_NODES, 98);
    scatter_k<<<(N_EDGES + 255) / 256, 256, 0, stream>>>(er, ec, ev, offs, cnt2, pcol, pval);
    row_k<<<(N_NODES * 64) / 256, 256, 0, stream>>>((const unsigned int*)h, offs, pcol, pval, out);
}

// Round 2
// 299.838 us; speedup vs baseline: 1.3021x; 1.3021x over previous
//
#include <hip/hip_runtime.h>

typedef short short8 __attribute__((ext_vector_type(8)));
typedef float f32x4 __attribute__((ext_vector_type(4)));

#define N_NODES 100000
#define N_EDGES 1600000
#define D_IN 256
#define D_OUT 128

// ws layout (bytes)
#define OFF_H     0UL          // bf16 h: 100000*128*2 = 25,600,000
#define OFF_WP    25600000UL   // packed W bf16 fragments: 65,536
#define OFF_OFFS  25665536UL   // int[100001] row offsets (+pad) = 400,016
#define OFF_CNT   26065552UL   // int[100000] counts = 400,000
#define OFF_CNT2  26465552UL   // int[100000] cursors = 400,000
#define OFF_BS    26865552UL   // int[1024] block sums = 4,096
#define OFF_PEV   26869648UL   // uint2[1.6M] (col, val-bits) = 12,800,000

__device__ __forceinline__ unsigned short f2bf(float f) {
    unsigned int u = __builtin_bit_cast(unsigned int, f);
    u += 0x7fffu + ((u >> 16) & 1u);   // RNE
    return (unsigned short)(u >> 16);
}

// Pack W [256][128] fp32 -> bf16 MFMA B-fragments.
// idx t = ks*512 + nt*64 + lane, elems e=0..7 at k=ks*32+(lane>>4)*8+e, n=nt*16+(lane&15)
__global__ void wpack_k(const float* __restrict__ W, unsigned short* __restrict__ wp) {
    int t = blockIdx.x * 256 + threadIdx.x;
    if (t >= 4096) return;
    int ks = t >> 9, nt = (t >> 6) & 7, lane = t & 63;
    int g = lane >> 4, n = nt * 16 + (lane & 15);
    int k0 = ks * 32 + g * 8;
#pragma unroll
    for (int e = 0; e < 8; ++e)
        wp[t * 8 + e] = f2bf(W[(size_t)(k0 + e) * D_OUT + n]);
}

// h = bf16( x @ W + b ), one 16-row tile per wave, full N=128 in registers.
__global__ __launch_bounds__(256) void gemm_k(const float* __restrict__ x,
                                              const short8* __restrict__ wq,
                                              const float* __restrict__ b,
                                              unsigned short* __restrict__ h) {
    int wave = threadIdx.x >> 6, lane = threadIdx.x & 63;
    int tile = blockIdx.x * 4 + wave;
    if (tile * 16 >= N_NODES) return;
    int row0 = tile * 16;
    int r = lane & 15, g = lane >> 4;

    f32x4 acc[8];
#pragma unroll
    for (int nt = 0; nt < 8; ++nt)
#pragma unroll
        for (int j = 0; j < 4; ++j) acc[nt][j] = 0.f;

    float bv[8];
#pragma unroll
    for (int nt = 0; nt < 8; ++nt) bv[nt] = b[nt * 16 + r];

    const float4* xp = (const float4*)(x + (size_t)(row0 + r) * D_IN);
#pragma unroll
    for (int ks = 0; ks < 8; ++ks) {
        float4 u0 = xp[ks * 8 + g * 2];
        float4 u1 = xp[ks * 8 + g * 2 + 1];
        short8 af;
        af[0] = (short)f2bf(u0.x); af[1] = (short)f2bf(u0.y);
        af[2] = (short)f2bf(u0.z); af[3] = (short)f2bf(u0.w);
        af[4] = (short)f2bf(u1.x); af[5] = (short)f2bf(u1.y);
        af[6] = (short)f2bf(u1.z); af[7] = (short)f2bf(u1.w);
#pragma unroll
        for (int nt = 0; nt < 8; ++nt) {
            short8 bf = wq[(ks * 8 + nt) * 64 + lane];
            acc[nt] = __builtin_amdgcn_mfma_f32_16x16x32_bf16(af, bf, acc[nt], 0, 0, 0);
        }
    }
#pragma unroll
    for (int nt = 0; nt < 8; ++nt)
#pragma unroll
        for (int j = 0; j < 4; ++j) {
            float v = acc[nt][j] + bv[nt];
            h[(size_t)(row0 + g * 4 + j) * D_OUT + nt * 16 + r] = f2bf(v);
        }
}

__global__ void count_k(const int* __restrict__ er, int* __restrict__ cnt) {
    int e = blockIdx.x * 256 + threadIdx.x;
    if (e < N_EDGES) atomicAdd(&cnt[er[e]], 1);
}

// Hillis-Steele inclusive scan per 1024-block; block sums out.
__global__ __launch_bounds__(1024) void scan1_k(const int* __restrict__ cnt, int* __restrict__ offs,
                                                int* __restrict__ bs, int n) {
    __shared__ int s[1024];
    int t = threadIdx.x;
    int i = blockIdx.x * 1024 + t;
    int v = (i < n) ? cnt[i] : 0;
    s[t] = v;
    __syncthreads();
    for (int off = 1; off < 1024; off <<= 1) {
        int tmp = (t >= off) ? s[t - off] : 0;
        __syncthreads();
        s[t] += tmp;
        __syncthreads();
    }
    if (i < n) offs[i] = s[t];
    if (t == 1023) bs[blockIdx.x] = s[1023];
}

__global__ void scan2_k(int* __restrict__ bs, int nb) {
    if (blockIdx.x == 0 && threadIdx.x == 0) {
        int run = 0;
        for (int bb = 0; bb < nb; ++bb) { int t = bs[bb]; bs[bb] = run; run += t; }
        bs[nb] = run;
    }
}

__global__ void scan3_k(int* __restrict__ offs, const int* __restrict__ cnt,
                        const int* __restrict__ bs, int n, int nb) {
    int i = blockIdx.x * 256 + threadIdx.x;
    if (i < n) offs[i] = offs[i] - cnt[i] + bs[i >> 10];
    if (i == 0) offs[n] = bs[nb];
}

__global__ void scatter_k(const int* __restrict__ er, const int* __restrict__ ec,
                          const float* __restrict__ ev, const int* __restrict__ offs,
                          int* __restrict__ cnt2, uint2* __restrict__ pev) {
    int e = blockIdx.x * 256 + threadIdx.x;
    if (e >= N_EDGES) return;
    int rrow = er[e];
    int pos = offs[rrow] + atomicAdd(&cnt2[rrow], 1);
    uint2 p;
    p.x = (unsigned int)ec[e];
    p.y = __builtin_bit_cast(unsigned int, ev[e]);
    pev[pos] = p;
}

// One wave per output row: out[i,:] = relu( sum_e val*h[col] ), 2 cols per lane.
// 8-deep unrolled gather for memory-level parallelism.
__global__ __launch_bounds__(256) void row_k(const unsigned int* __restrict__ h32,
                                             const int* __restrict__ offs,
                                             const uint2* __restrict__ pev,
                                             float* __restrict__ out) {
    int gw = (blockIdx.x * 256 + threadIdx.x) >> 6;
    int lane = threadIdx.x & 63;
    if (gw >= N_NODES) return;
    int s = offs[gw], e2 = offs[gw + 1];
    float accA[4] = {0.f, 0.f, 0.f, 0.f};
    float accB[4] = {0.f, 0.f, 0.f, 0.f};
    int e = s;
    for (; e + 8 <= e2; e += 8) {
        uint2 p[8];
#pragma unroll
        for (int i = 0; i < 8; ++i) p[i] = pev[e + i];
        unsigned int hv[8];
#pragma unroll
        for (int i = 0; i < 8; ++i) hv[i] = h32[(size_t)p[i].x * 64 + lane];
#pragma unroll
        for (int i = 0; i < 8; ++i) {
            float v = __builtin_bit_cast(float, p[i].y);
            accA[i & 3] += v * __builtin_bit_cast(float, hv[i] << 16);
            accB[i & 3] += v * __builtin_bit_cast(float, hv[i] & 0xffff0000u);
        }
    }
    for (; e < e2; ++e) {
        uint2 p = pev[e];
        float v = __builtin_bit_cast(float, p.y);
        unsigned int hv = h32[(size_t)p.x * 64 + lane];
        accA[0] += v * __builtin_bit_cast(float, hv << 16);
        accB[0] += v * __builtin_bit_cast(float, hv & 0xffff0000u);
    }
    float a = (accA[0] + accA[1]) + (accA[2] + accA[3]);
    float bb = (accB[0] + accB[1]) + (accB[2] + accB[3]);
    float2 o;
    o.x = a > 0.f ? a : 0.f;
    o.y = bb > 0.f ? bb : 0.f;
    reinterpret_cast<float2*>(out)[(size_t)gw * 64 + lane] = o;
}

extern "C" void kernel_launch(void* const* d_in, const int* in_sizes, int n_in,
                              void* d_out, int out_size, void* d_ws, size_t ws_size,
                              hipStream_t stream) {
    const float* x = (const float*)d_in[0];
    const float* W = (const float*)d_in[1];
    const float* b = (const float*)d_in[2];
    const int* er = (const int*)d_in[3];
    const int* ec = (const int*)d_in[4];
    const float* ev = (const float*)d_in[5];
    float* out = (float*)d_out;
    char* ws = (char*)d_ws;

    unsigned short* h = (unsigned short*)(ws + OFF_H);
    unsigned short* wp = (unsigned short*)(ws + OFF_WP);
    int* offs = (int*)(ws + OFF_OFFS);
    int* cnt = (int*)(ws + OFF_CNT);
    int* cnt2 = (int*)(ws + OFF_CNT2);
    int* bs = (int*)(ws + OFF_BS);
    uint2* pev = (uint2*)(ws + OFF_PEV);

    hipMemsetAsync(ws + OFF_CNT, 0, 800000, stream);  // cnt + cnt2

    wpack_k<<<16, 256, 0, stream>>>(W, wp);
    gemm_k<<<1563, 256, 0, stream>>>(x, (const short8*)wp, b, h);
    count_k<<<(N_EDGES + 255) / 256, 256, 0, stream>>>(er, cnt);
    scan1_k<<<98, 1024, 0, stream>>>(cnt, offs, bs, N_NODES);
    scan2_k<<<1, 64, 0, stream>>>(bs, 98);
    scan3_k<<<(N_NODES + 255) / 256, 256, 0, stream>>>(offs, cnt, bs, N_NODES, 98);
    scatter_k<<<(N_EDGES + 255) / 256, 256, 0, stream>>>(er, ec, ev, offs, cnt2, pev);
    row_k<<<(N_NODES * 64) / 256, 256, 0, stream>>>((const unsigned int*)h, offs, pev, out);
}